// Round 1
// baseline (5525.310 us; speedup 1.0000x reference)
//
#include <hip/hip_runtime.h>

#define NV   100000
#define NE   50000
#define NNZ  3200000
#define KIN  256
#define KOUT 64

// ---------------------------------------------------------------------------
// Kernel 1: Xp[r][o] = sum_k X[r][k] * W[o][k]
// Block = 256 threads, computes 64 rows x 64 ch.
// Thread layout: g = tid/16 -> rows rbase+4g..+3 ; t16 = tid%16 -> ch 4*t16..+3
// W staged transposed in LDS: Wt[k][o] (64 KB), float4 reads conflict-light.
// ---------------------------------------------------------------------------
__global__ __launch_bounds__(256) void k_project(const float* __restrict__ X,
                                                 const float* __restrict__ W,
                                                 float* __restrict__ Xp) {
    __shared__ float Wt[KIN][KOUT];   // 64 KB
    const int tid = threadIdx.x;

    // Stage W transposed: consecutive tid -> consecutive o => conflict-free
    // LDS writes; global reads are strided but W is tiny (64 KB, L2-resident).
    for (int i = tid; i < KIN * KOUT; i += 256) {
        int o = i & 63;
        int k = i >> 6;
        Wt[k][o] = W[o * KIN + k];
    }
    __syncthreads();

    const int g   = tid >> 4;          // 0..15 row group
    const int t16 = tid & 15;
    const int ch0 = t16 << 2;          // channel base (multiple of 4)
    const int rbase = blockIdx.x * 64 + g * 4;

    const float4* xp[4];
#pragma unroll
    for (int i = 0; i < 4; ++i) {
        int rr = rbase + i;
        if (rr > NV - 1) rr = NV - 1;  // clamp reads; stores guarded below
        xp[i] = (const float4*)(X + (size_t)rr * KIN);
    }

    float acc[4][4];
#pragma unroll
    for (int i = 0; i < 4; ++i)
#pragma unroll
        for (int c = 0; c < 4; ++c) acc[i][c] = 0.0f;

    for (int kk = 0; kk < KIN / 4; ++kk) {
        float4 w[4];
#pragma unroll
        for (int j = 0; j < 4; ++j)
            w[j] = *(const float4*)&Wt[4 * kk + j][ch0];

#pragma unroll
        for (int i = 0; i < 4; ++i) {
            float4 x = xp[i][kk];
            float xs0 = x.x, xs1 = x.y, xs2 = x.z, xs3 = x.w;
            acc[i][0] = fmaf(xs0, w[0].x, acc[i][0]);
            acc[i][1] = fmaf(xs0, w[0].y, acc[i][1]);
            acc[i][2] = fmaf(xs0, w[0].z, acc[i][2]);
            acc[i][3] = fmaf(xs0, w[0].w, acc[i][3]);
            acc[i][0] = fmaf(xs1, w[1].x, acc[i][0]);
            acc[i][1] = fmaf(xs1, w[1].y, acc[i][1]);
            acc[i][2] = fmaf(xs1, w[1].z, acc[i][2]);
            acc[i][3] = fmaf(xs1, w[1].w, acc[i][3]);
            acc[i][0] = fmaf(xs2, w[2].x, acc[i][0]);
            acc[i][1] = fmaf(xs2, w[2].y, acc[i][1]);
            acc[i][2] = fmaf(xs2, w[2].z, acc[i][2]);
            acc[i][3] = fmaf(xs2, w[2].w, acc[i][3]);
            acc[i][0] = fmaf(xs3, w[3].x, acc[i][0]);
            acc[i][1] = fmaf(xs3, w[3].y, acc[i][1]);
            acc[i][2] = fmaf(xs3, w[3].z, acc[i][2]);
            acc[i][3] = fmaf(xs3, w[3].w, acc[i][3]);
        }
    }

#pragma unroll
    for (int i = 0; i < 4; ++i) {
        int r = rbase + i;
        if (r < NV) {
            float4 o = make_float4(acc[i][0], acc[i][1], acc[i][2], acc[i][3]);
            *(float4*)&Xp[(size_t)r * KOUT + ch0] = o;
        }
    }
}

// ---------------------------------------------------------------------------
// Kernel 2: Xe[e] += Xp[v]  (atomic scatter, 16 threads per nnz, float4 each)
// Grid is exactly NNZ*16/256 = 200000 blocks -> no guard needed.
// ---------------------------------------------------------------------------
__global__ __launch_bounds__(256) void k_scatter1(const float* __restrict__ Xp,
                                                  const int* __restrict__ v_idx,
                                                  const int* __restrict__ e_idx,
                                                  float* __restrict__ Xe) {
    const int i = blockIdx.x * 256 + threadIdx.x;
    const int n = i >> 4;
    const int c = (i & 15) << 2;
    const int v = v_idx[n];
    const int e = e_idx[n];
    const float4 x = *(const float4*)&Xp[(size_t)v * KOUT + c];
    float* dst = &Xe[(size_t)e * KOUT + c];
    atomicAdd(dst + 0, x.x);
    atomicAdd(dst + 1, x.y);
    atomicAdd(dst + 2, x.z);
    atomicAdd(dst + 3, x.w);
}

// ---------------------------------------------------------------------------
// Kernel 3: out[v] += degV[v]*degE[e]*Wdiag[e] * Xe[e]
// (degE*Wdiag fused at gather; degV distributed into each contribution)
// ---------------------------------------------------------------------------
__global__ __launch_bounds__(256) void k_scatter2(const float* __restrict__ Xe,
                                                  const int* __restrict__ v_idx,
                                                  const int* __restrict__ e_idx,
                                                  const float* __restrict__ degE,
                                                  const float* __restrict__ degV,
                                                  const float* __restrict__ Wdiag,
                                                  float* __restrict__ out) {
    const int i = blockIdx.x * 256 + threadIdx.x;
    const int n = i >> 4;
    const int c = (i & 15) << 2;
    const int v = v_idx[n];
    const int e = e_idx[n];
    const float s = degE[e] * Wdiag[e] * degV[v];
    const float4 x = *(const float4*)&Xe[(size_t)e * KOUT + c];
    float* dst = &out[(size_t)v * KOUT + c];
    atomicAdd(dst + 0, s * x.x);
    atomicAdd(dst + 1, s * x.y);
    atomicAdd(dst + 2, s * x.z);
    atomicAdd(dst + 3, s * x.w);
}

extern "C" void kernel_launch(void* const* d_in, const int* in_sizes, int n_in,
                              void* d_out, int out_size, void* d_ws, size_t ws_size,
                              hipStream_t stream) {
    const float* X     = (const float*)d_in[0];
    const float* W     = (const float*)d_in[1];
    const float* degE  = (const float*)d_in[2];
    const float* degV  = (const float*)d_in[3];
    const float* Wdiag = (const float*)d_in[4];
    const int*   v_idx = (const int*)d_in[5];
    const int*   e_idx = (const int*)d_in[6];
    float* out = (float*)d_out;

    float* Xp = (float*)d_ws;                    // NV*KOUT  = 6.4M floats (25.6 MB)
    float* Xe = Xp + (size_t)NV * KOUT;          // NE*KOUT  = 3.2M floats (12.8 MB)

    hipMemsetAsync(Xe, 0, (size_t)NE * KOUT * sizeof(float), stream);
    hipMemsetAsync(out, 0, (size_t)NV * KOUT * sizeof(float), stream);

    k_project<<<(NV + 63) / 64, 256, 0, stream>>>(X, W, Xp);

    const int nblk = (NNZ * 16) / 256;           // 200000, exact
    k_scatter1<<<nblk, 256, 0, stream>>>(Xp, v_idx, e_idx, Xe);
    k_scatter2<<<nblk, 256, 0, stream>>>(Xe, v_idx, e_idx, degE, degV, Wdiag, out);
}

// Round 2
// 1524.929 us; speedup vs baseline: 3.6233x; 3.6233x over previous
//
#include <hip/hip_runtime.h>

#define NV   100000
#define NE   50000
#define NNZ  3200000
#define KIN  256
#define KOUT 64

// ---------------------------------------------------------------------------
// Kernel 1: Xp[r][o] = sum_k X[r][k] * W[o][k]   (unchanged from round 1)
// ---------------------------------------------------------------------------
__global__ __launch_bounds__(256) void k_project(const float* __restrict__ X,
                                                 const float* __restrict__ W,
                                                 float* __restrict__ Xp) {
    __shared__ float Wt[KIN][KOUT];   // 64 KB
    const int tid = threadIdx.x;
    for (int i = tid; i < KIN * KOUT; i += 256) {
        int o = i & 63;
        int k = i >> 6;
        Wt[k][o] = W[o * KIN + k];
    }
    __syncthreads();

    const int g   = tid >> 4;
    const int t16 = tid & 15;
    const int ch0 = t16 << 2;
    const int rbase = blockIdx.x * 64 + g * 4;

    const float4* xp[4];
#pragma unroll
    for (int i = 0; i < 4; ++i) {
        int rr = rbase + i;
        if (rr > NV - 1) rr = NV - 1;
        xp[i] = (const float4*)(X + (size_t)rr * KIN);
    }

    float acc[4][4];
#pragma unroll
    for (int i = 0; i < 4; ++i)
#pragma unroll
        for (int c = 0; c < 4; ++c) acc[i][c] = 0.0f;

    for (int kk = 0; kk < KIN / 4; ++kk) {
        float4 w[4];
#pragma unroll
        for (int j = 0; j < 4; ++j)
            w[j] = *(const float4*)&Wt[4 * kk + j][ch0];
#pragma unroll
        for (int i = 0; i < 4; ++i) {
            float4 x = xp[i][kk];
            acc[i][0] = fmaf(x.x, w[0].x, acc[i][0]);
            acc[i][1] = fmaf(x.x, w[0].y, acc[i][1]);
            acc[i][2] = fmaf(x.x, w[0].z, acc[i][2]);
            acc[i][3] = fmaf(x.x, w[0].w, acc[i][3]);
            acc[i][0] = fmaf(x.y, w[1].x, acc[i][0]);
            acc[i][1] = fmaf(x.y, w[1].y, acc[i][1]);
            acc[i][2] = fmaf(x.y, w[1].z, acc[i][2]);
            acc[i][3] = fmaf(x.y, w[1].w, acc[i][3]);
            acc[i][0] = fmaf(x.z, w[2].x, acc[i][0]);
            acc[i][1] = fmaf(x.z, w[2].y, acc[i][1]);
            acc[i][2] = fmaf(x.z, w[2].z, acc[i][2]);
            acc[i][3] = fmaf(x.z, w[2].w, acc[i][3]);
            acc[i][0] = fmaf(x.w, w[3].x, acc[i][0]);
            acc[i][1] = fmaf(x.w, w[3].y, acc[i][1]);
            acc[i][2] = fmaf(x.w, w[3].z, acc[i][2]);
            acc[i][3] = fmaf(x.w, w[3].w, acc[i][3]);
        }
    }

#pragma unroll
    for (int i = 0; i < 4; ++i) {
        int r = rbase + i;
        if (r < NV) {
            float4 o = make_float4(acc[i][0], acc[i][1], acc[i][2], acc[i][3]);
            *(float4*)&Xp[(size_t)r * KOUT + ch0] = o;
        }
    }
}

// ---------------------------------------------------------------------------
// CSR build: histogram both keys in one pass (int atomics, cheap)
// ---------------------------------------------------------------------------
__global__ __launch_bounds__(256) void k_count(const int* __restrict__ v_idx,
                                               const int* __restrict__ e_idx,
                                               int* __restrict__ cntE,
                                               int* __restrict__ cntV) {
    const int i = blockIdx.x * 256 + threadIdx.x;
    if (i < NNZ) {
        atomicAdd(&cntE[e_idx[i]], 1);
        atomicAdd(&cntV[v_idx[i]], 1);
    }
}

// Single-block exclusive scan of cnt[0..n) -> off[0..n], cur[0..n)=off copy.
__device__ void scan_one(const int* __restrict__ cnt, int* __restrict__ off,
                         int* __restrict__ cur, int n) {
    __shared__ int buf[1024];
    __shared__ int carry_s;
    const int tid = threadIdx.x;
    if (tid == 0) carry_s = 0;
    __syncthreads();
    for (int base = 0; base < n; base += 1024) {
        const int i = base + tid;
        const int v = (i < n) ? cnt[i] : 0;
        buf[tid] = v;
        __syncthreads();
        for (int d = 1; d < 1024; d <<= 1) {
            int t = (tid >= d) ? buf[tid - d] : 0;
            __syncthreads();
            buf[tid] += t;
            __syncthreads();
        }
        const int carry = carry_s;
        if (i < n) {
            const int excl = carry + buf[tid] - v;
            off[i] = excl;
            cur[i] = excl;
        }
        __syncthreads();
        if (tid == 1023) carry_s = carry + buf[1023];
        __syncthreads();
    }
    if (tid == 0) off[n] = carry_s;
    __syncthreads();
}

__global__ __launch_bounds__(1024) void k_scan_both(const int* cntE, int* offE, int* curE,
                                                    const int* cntV, int* offV, int* curV) {
    scan_one(cntE, offE, curE, NE);
    scan_one(cntV, offV, curV, NV);
}

__global__ __launch_bounds__(256) void k_fillE(const int* __restrict__ v_idx,
                                               const int* __restrict__ e_idx,
                                               int* __restrict__ curE,
                                               int* __restrict__ adj) {
    const int i = blockIdx.x * 256 + threadIdx.x;
    if (i < NNZ) {
        const int p = atomicAdd(&curE[e_idx[i]], 1);
        adj[p] = v_idx[i];
    }
}

__global__ __launch_bounds__(256) void k_fillV(const int* __restrict__ v_idx,
                                               const int* __restrict__ e_idx,
                                               int* __restrict__ curV,
                                               int* __restrict__ adj) {
    const int i = blockIdx.x * 256 + threadIdx.x;
    if (i < NNZ) {
        const int p = atomicAdd(&curV[v_idx[i]], 1);
        adj[p] = e_idx[i];
    }
}

// ---------------------------------------------------------------------------
// Stage 1 (pull): one wave per edge; lane = channel.
// Xe[e][lane] = (degE[e]*Wdiag[e]) * sum_{v in adjE[e]} Xp[v][lane]
// Indices fetched 64-at-a-time into lanes, broadcast via shfl.
// ---------------------------------------------------------------------------
__global__ __launch_bounds__(256) void k_gatherE(const float* __restrict__ Xp,
                                                 const int* __restrict__ offE,
                                                 const int* __restrict__ adj,
                                                 const float* __restrict__ degE,
                                                 const float* __restrict__ Wdiag,
                                                 float* __restrict__ Xe) {
    const int wave = (blockIdx.x * 256 + threadIdx.x) >> 6;
    const int lane = threadIdx.x & 63;
    if (wave >= NE) return;
    const int b = offE[wave];
    const int e = offE[wave + 1];
    float acc = 0.0f;
    for (int base = b; base < e; base += 64) {
        const int m = min(64, e - base);
        const int vi = (base + lane < e) ? adj[base + lane] : 0;
        for (int t = 0; t < m; ++t) {
            const int v = __shfl(vi, t, 64);
            acc += Xp[(size_t)v * KOUT + lane];
        }
    }
    Xe[(size_t)wave * KOUT + lane] = acc * (degE[wave] * Wdiag[wave]);
}

// ---------------------------------------------------------------------------
// Stage 2 (pull): one wave per vertex.
// out[v][lane] = degV[v] * sum_{e in adjV[v]} Xe[e][lane]
// ---------------------------------------------------------------------------
__global__ __launch_bounds__(256) void k_gatherV(const float* __restrict__ Xe,
                                                 const int* __restrict__ offV,
                                                 const int* __restrict__ adj,
                                                 const float* __restrict__ degV,
                                                 float* __restrict__ out) {
    const int wave = (blockIdx.x * 256 + threadIdx.x) >> 6;
    const int lane = threadIdx.x & 63;
    if (wave >= NV) return;
    const int b = offV[wave];
    const int e = offV[wave + 1];
    float acc = 0.0f;
    for (int base = b; base < e; base += 64) {
        const int m = min(64, e - base);
        const int ei = (base + lane < e) ? adj[base + lane] : 0;
        for (int t = 0; t < m; ++t) {
            const int ee = __shfl(ei, t, 64);
            acc += Xe[(size_t)ee * KOUT + lane];
        }
    }
    out[(size_t)wave * KOUT + lane] = acc * degV[wave];
}

extern "C" void kernel_launch(void* const* d_in, const int* in_sizes, int n_in,
                              void* d_out, int out_size, void* d_ws, size_t ws_size,
                              hipStream_t stream) {
    const float* X     = (const float*)d_in[0];
    const float* W     = (const float*)d_in[1];
    const float* degE  = (const float*)d_in[2];
    const float* degV  = (const float*)d_in[3];
    const float* Wdiag = (const float*)d_in[4];
    const int*   v_idx = (const int*)d_in[5];
    const int*   e_idx = (const int*)d_in[6];
    float* out = (float*)d_out;

    // Workspace layout (~53 MB)
    float* Xp  = (float*)d_ws;                      // NV*KOUT floats
    float* Xe  = Xp + (size_t)NV * KOUT;            // NE*KOUT floats
    int*   adj = (int*)(Xe + (size_t)NE * KOUT);    // NNZ ints (reused E then V)
    int*   offE = adj + NNZ;                        // NE+1
    int*   offV = offE + (NE + 1);                  // NV+1
    int*   cntE = offV + (NV + 1);                  // NE
    int*   cntV = cntE + NE;                        // NV
    int*   curE = cntV + NV;                        // NE
    int*   curV = curE + NE;                        // NV

    // Zero both histograms in one memset (cntE,cntV contiguous)
    hipMemsetAsync(cntE, 0, (size_t)(NE + NV) * sizeof(int), stream);

    k_project<<<(NV + 63) / 64, 256, 0, stream>>>(X, W, Xp);

    const int nblk_nnz = (NNZ + 255) / 256;   // 12500 (exact)
    k_count<<<nblk_nnz, 256, 0, stream>>>(v_idx, e_idx, cntE, cntV);
    k_scan_both<<<1, 1024, 0, stream>>>(cntE, offE, curE, cntV, offV, curV);

    // Edge CSR -> stage 1
    k_fillE<<<nblk_nnz, 256, 0, stream>>>(v_idx, e_idx, curE, adj);
    k_gatherE<<<(NE * 64 + 255) / 256, 256, 0, stream>>>(Xp, offE, adj, degE, Wdiag, Xe);

    // Vertex CSR (reuses adj) -> stage 2
    k_fillV<<<nblk_nnz, 256, 0, stream>>>(v_idx, e_idx, curV, adj);
    k_gatherV<<<(NV * 64 + 255) / 256, 256, 0, stream>>>(Xe, offV, adj, degV, out);
}